// Round 6
// baseline (899.656 us; speedup 1.0000x reference)
//
#include <hip/hip_runtime.h>
#include <stdint.h>

// ---------- types / helpers ----------
typedef __attribute__((ext_vector_type(8))) short short8;   // 8 x bf16 bits
typedef __attribute__((ext_vector_type(4))) float f32x4;

__device__ __forceinline__ unsigned short f2bf(float f) {
  unsigned u = __float_as_uint(f);
  u += 0x7fffu + ((u >> 16) & 1u);           // round-to-nearest-even
  return (unsigned short)(u >> 16);
}
__device__ __forceinline__ float bf2f(unsigned short u) {
  return __uint_as_float(((unsigned)u) << 16);
}

// ---------- kernel 1: BT[n][k] = bf16(W1[(n>=512? 512:0)+k][n&511]) ----------
// BT is [1024][512] bf16, n-major; GEMM computes P[m][n] = sum_k A[m][k]*BT[n][k]
__global__ void __launch_bounds__(256) buildBT_kernel(const float* __restrict__ W1,
                                                      unsigned short* __restrict__ BT) {
  int t = blockIdx.x * 256 + threadIdx.x;   // 0..524287
  int n = t >> 9;
  int k = t & 511;
  float v = W1[((size_t)((n >> 9) * 512 + k)) * 512 + (size_t)(n & 511)];
  BT[t] = f2bf(v);
}

// ---------- kernel 2: fused cast + strip-resident GEMM ----------
// Block = 64-row strip of h. Phase 1: h(f32) -> bf16 -> LDS (chunk-XOR swizzle),
// ONE barrier. Phase 2: nb(8) x kt(8) loop, A-frags from LDS, B-frags from
// global (L1/L2-hot), acc in regs, ZERO barriers. Direct u16 stores.
// 512 threads = 8 waves as 4M x 2N (each wave: 16 rows x 64 cols per nb).
__global__ void __launch_bounds__(512, 4) gemm2_kernel(const float* __restrict__ h,
                                                       const unsigned short* __restrict__ BT,
                                                       const float* __restrict__ b1,
                                                       unsigned short* __restrict__ P,
                                                       int M) {
  __shared__ unsigned short As[64 * 512];   // 64 KB bf16 A-strip

  const int tid = threadIdx.x;
  const int m0  = blockIdx.x * 64;

  // ---- phase 1: A-init (cast fused) ----
  {
    int idx = tid;                      // 8192 16B-chunks, 16 iters x 512 threads
#pragma unroll
    for (int it = 0; it < 16; ++it, idx += 512) {
      const int row = idx >> 7;         // 0..63
      const int c8  = idx & 127;        // which float4 within the row
      int gr = m0 + row; gr = gr < M ? gr : M - 1;
      const float4 v = *(const float4*)(h + (size_t)gr * 512 + c8 * 4);
      unsigned lo, hi;
      asm("v_cvt_pk_bf16_f32 %0, %1, %2" : "=v"(lo) : "v"(v.x), "v"(v.y));
      asm("v_cvt_pk_bf16_f32 %0, %1, %2" : "=v"(hi) : "v"(v.z), "v"(v.w));
      // chunk-XOR swizzle: 16B chunk c = c8>>1 stored at (c ^ (row&7)) in low 3 bits
      const int soff = row * 512 + (((c8 >> 1) ^ (row & 7)) << 3) + (c8 & 1) * 4;
      *(uint2*)(As + soff) = make_uint2(lo, hi);
    }
  }
  __syncthreads();                      // the ONLY barrier

  // ---- phase 2: barrier-free MFMA loop ----
  const int lane = tid & 63;
  const int wid  = tid >> 6;            // 0..7
  const int wr   = wid & 3;             // 4 M-ranges of 16 rows
  const int wc   = wid >> 2;            // 2 N-ranges of 64 cols
  const int lr   = lane & 15;
  const int g    = lane >> 4;           // 0..3

  const int arow = wr * 16 + lr;        // A row within strip
  const int a7   = arow & 7;
  const unsigned short* Arow = As + arow * 512;

#pragma unroll 1
  for (int nb = 0; nb < 8; ++nb) {
    f32x4 acc[4];
#pragma unroll
    for (int nf = 0; nf < 4; ++nf) acc[nf] = (f32x4){0.f, 0.f, 0.f, 0.f};

    const unsigned short* Bb = BT + (size_t)(nb * 128 + wc * 64 + lr) * 512;

#pragma unroll 2
    for (int kt = 0; kt < 8; ++kt) {
      const int kb = kt * 64;
      short8 bF[4][2];
#pragma unroll
      for (int nf = 0; nf < 4; ++nf) {
        bF[nf][0] = *(const short8*)(Bb + (size_t)nf * 8192 + kb + g * 8);
        bF[nf][1] = *(const short8*)(Bb + (size_t)nf * 8192 + kb + 32 + g * 8);
      }
      const short8 aF0 = *(const short8*)(Arow + ((kt * 8 + (g ^ a7)) << 3));
      const short8 aF1 = *(const short8*)(Arow + ((kt * 8 + ((4 + g) ^ a7)) << 3));
#pragma unroll
      for (int nf = 0; nf < 4; ++nf) {
        acc[nf] = __builtin_amdgcn_mfma_f32_16x16x32_bf16(aF0, bF[nf][0], acc[nf], 0, 0, 0);
        acc[nf] = __builtin_amdgcn_mfma_f32_16x16x32_bf16(aF1, bF[nf][1], acc[nf], 0, 0, 0);
      }
    }

    // per-nb epilogue: bias (cols<512 <=> nb<4), direct u16 stores
    const int colb = nb * 128 + wc * 64;
#pragma unroll
    for (int nf = 0; nf < 4; ++nf) {
      const int col = colb + nf * 16 + lr;
      const float bias = (nb < 4) ? b1[col] : 0.0f;
#pragma unroll
      for (int ri = 0; ri < 4; ++ri) {
        const int grow = m0 + wr * 16 + g * 4 + ri;
        if (grow < M) P[(size_t)grow * 1024 + col] = f2bf(acc[nf][ri] + bias);
      }
    }
  }
}

// ---------- kernel 3: per-edge score ----------
// score[e] = b2 + sum_j relu(P[src][j] + P[dst][512+j]) * W2[j]
__global__ void __launch_bounds__(256) edge_kernel(const unsigned short* __restrict__ P,
                                                   const int* __restrict__ src,
                                                   const int* __restrict__ dst,
                                                   const float* __restrict__ W2,
                                                   const float* __restrict__ b2,
                                                   float* __restrict__ out,
                                                   int E) {
  const int gw   = (blockIdx.x * 256 + threadIdx.x) >> 6;   // global wave = edge
  const int lane = threadIdx.x & 63;
  if (gw >= E) return;
  const int s = src[gw];
  const int d = dst[gw];
  const short8 va = *(const short8*)(P + (size_t)s * 1024 + lane * 8);
  const short8 vb = *(const short8*)(P + (size_t)d * 1024 + 512 + lane * 8);
  const float4 w0 = *(const float4*)(W2 + lane * 8);
  const float4 w1 = *(const float4*)(W2 + lane * 8 + 4);
  float a = 0.f, x;
  x = bf2f((unsigned short)va[0]) + bf2f((unsigned short)vb[0]); a += fmaxf(x, 0.f) * w0.x;
  x = bf2f((unsigned short)va[1]) + bf2f((unsigned short)vb[1]); a += fmaxf(x, 0.f) * w0.y;
  x = bf2f((unsigned short)va[2]) + bf2f((unsigned short)vb[2]); a += fmaxf(x, 0.f) * w0.z;
  x = bf2f((unsigned short)va[3]) + bf2f((unsigned short)vb[3]); a += fmaxf(x, 0.f) * w0.w;
  x = bf2f((unsigned short)va[4]) + bf2f((unsigned short)vb[4]); a += fmaxf(x, 0.f) * w1.x;
  x = bf2f((unsigned short)va[5]) + bf2f((unsigned short)vb[5]); a += fmaxf(x, 0.f) * w1.y;
  x = bf2f((unsigned short)va[6]) + bf2f((unsigned short)vb[6]); a += fmaxf(x, 0.f) * w1.z;
  x = bf2f((unsigned short)va[7]) + bf2f((unsigned short)vb[7]); a += fmaxf(x, 0.f) * w1.w;
#pragma unroll
  for (int o = 32; o > 0; o >>= 1) a += __shfl_down(a, o);
  if (lane == 0) out[gw] = a + b2[0];
}

// ---------- launcher ----------
extern "C" void kernel_launch(void* const* d_in, const int* in_sizes, int n_in,
                              void* d_out, int out_size, void* d_ws, size_t ws_size,
                              hipStream_t stream) {
  const float* h  = (const float*)d_in[0];
  const int*   src = (const int*)d_in[1];
  const int*   dst = (const int*)d_in[2];
  const float* W1 = (const float*)d_in[3];
  const float* b1 = (const float*)d_in[4];
  const float* W2 = (const float*)d_in[5];
  const float* b2 = (const float*)d_in[6];
  float* out = (float*)d_out;

  const int M = in_sizes[0] / 512;   // 100000 nodes
  const int E = in_sizes[1];         // 160000 edges

  char* ws = (char*)d_ws;
  unsigned short* BT = (unsigned short*)ws;                          // 1024*512 bf16 = 1MB
  unsigned short* P  = (unsigned short*)(ws + (size_t)1024 * 512 * 2);  // M*1024 bf16

  buildBT_kernel<<<2048, 256, 0, stream>>>(W1, BT);
  const int Gm = (M + 63) / 64;                 // 1563 strips
  gemm2_kernel<<<Gm, 512, 0, stream>>>(h, BT, b1, P, M);
  edge_kernel<<<(E + 3) / 4, 256, 0, stream>>>(P, src, dst, W2, b2, out, E);
}

// Round 7
// 275.189 us; speedup vs baseline: 3.2692x; 3.2692x over previous
//
#include <hip/hip_runtime.h>
#include <stdint.h>

// ---------- types / helpers ----------
typedef __attribute__((ext_vector_type(8))) short short8;   // 8 x bf16 bits
typedef __attribute__((ext_vector_type(4))) float f32x4;

__device__ __forceinline__ unsigned short f2bf(float f) {
  unsigned u = __float_as_uint(f);
  u += 0x7fffu + ((u >> 16) & 1u);           // round-to-nearest-even
  return (unsigned short)(u >> 16);
}
__device__ __forceinline__ float bf2f(unsigned short u) {
  return __uint_as_float(((unsigned)u) << 16);
}

#define GLDS16(gp, lp)                                              \
  __builtin_amdgcn_global_load_lds(                                  \
      (const __attribute__((address_space(1))) void*)(gp),           \
      (__attribute__((address_space(3))) void*)(lp), 16, 0, 0)

// ---------- kernel 1: BT[n][k] = bf16(W1[(n>=512? 512:0)+k][n&511]) ----------
__global__ void __launch_bounds__(256) buildBT_kernel(const float* __restrict__ W1,
                                                      unsigned short* __restrict__ BT) {
  int t = blockIdx.x * 256 + threadIdx.x;   // 0..524287
  int n = t >> 9;
  int k = t & 511;
  float v = W1[((size_t)((n >> 9) * 512 + k)) * 512 + (size_t)(n & 511)];
  BT[t] = f2bf(v);
}

// ---------- kernel 2: FUSED cast + GEMM ----------
// P[M][1024](bf16) = bf16(h[M][512]) @ BT^T (+b1 cols<512)
// Round-2 proven core: 128x128 tile, BK=64, 256 thr (4 waves, 64x64/wave),
// XOR-swizzled LDS, LDS-repack epilogue. New: A staged from h(f32) via
// reg-prefetch (1 k-tile ahead, vmcnt(4)) + v_cvt_pk_bf16_f32 + ds_write;
// B double-buffered via global_load_lds (1 k-tile ahead, vmcnt(12)).
__global__ void __launch_bounds__(256) gemmF_kernel(const float* __restrict__ h,
                                                    const unsigned short* __restrict__ BT,
                                                    const float* __restrict__ b1,
                                                    unsigned short* __restrict__ P,
                                                    int M) {
  __shared__ unsigned short As[128 * 64];      // 16 KB (single buffer)
  __shared__ unsigned short Bs[2][128 * 64];   // 2 x 16 KB (double buffer)

  // --- XCD-chunked block swizzle; n-tile fastest within an A strip ---
  const int nwg = gridDim.x;                // Mtiles*8, divisible by 8
  const int cpx = nwg >> 3;
  const int wg  = (blockIdx.x & 7) * cpx + (blockIdx.x >> 3);
  const int nt  = wg & 7;
  const int mt  = wg >> 3;
  const int m0  = mt * 128;
  const int n0  = nt * 128;

  const int tid  = threadIdx.x;
  const int lane = tid & 63;
  const int wid  = tid >> 6;
  const int wr   = wid >> 1, wc = wid & 1;
  const int lr   = lane & 15;
  const int g    = lane >> 4;      // 0..3

  // --- B staging constants (gload_lds; wave-uniform base + lane*16) ---
  const int srowB = tid >> 3;      // 0..31
  const int slotB = tid & 7;

  // --- A staging constants: 16 threads/row, 8 row-passes; coalesced 256B rows ---
  const int c16  = tid & 15;       // 8B-granule within the 64-elem k-range
  const int rsub = tid >> 4;       // 0..15
  const float* hp[8];
  unsigned wA[8];
#pragma unroll
  for (int j = 0; j < 8; ++j) {
    const int r = j * 16 + rsub;   // A-tile row 0..127
    int gr = m0 + r; gr = gr < M ? gr : M - 1;     // clamp: uniform load count
    hp[j] = h + (size_t)gr * 512 + c16 * 4;
    wA[j] = (unsigned)(r * 128 + (((c16 >> 1) ^ (r & 7)) << 4) + (c16 & 1) * 8);
  }

  float4 ap[8];
#define AP_LOAD(kt)                                                   \
  { _Pragma("unroll") for (int j = 0; j < 8; ++j)                     \
      ap[j] = *(const float4*)(hp[j] + (kt) * 64); }

#define CVT_WRITE_A()                                                 \
  { _Pragma("unroll") for (int j = 0; j < 8; ++j) {                   \
      unsigned lo_, hi_;                                              \
      asm("v_cvt_pk_bf16_f32 %0, %1, %2" : "=v"(lo_) : "v"(ap[j].x), "v"(ap[j].y)); \
      asm("v_cvt_pk_bf16_f32 %0, %1, %2" : "=v"(hi_) : "v"(ap[j].z), "v"(ap[j].w)); \
      *(uint2*)((char*)As + wA[j]) = make_uint2(lo_, hi_); } }

#define STAGE_B(kt, buf)                                              \
  { const int k0_ = (kt) * 64;                                        \
    _Pragma("unroll") for (int q = 0; q < 4; ++q) {                   \
      const int row_ = q * 32 + srowB;                                \
      const int gk_  = k0_ + ((slotB ^ (row_ & 7)) << 3);             \
      GLDS16(BT + (size_t)(n0 + row_) * 512 + gk_,                    \
             &Bs[buf][row_ * 64 + slotB * 8]); } }

  f32x4 acc[4][4];
#pragma unroll
  for (int i = 0; i < 4; ++i)
#pragma unroll
    for (int j = 0; j < 4; ++j) acc[i][j] = (f32x4){0.f, 0.f, 0.f, 0.f};

  // --- prologue ---
  AP_LOAD(0)                       // 8 f32 loads (A tile 0)
  STAGE_B(0, 0)                    // 4 glds
  asm volatile("s_waitcnt vmcnt(4)" ::: "memory");   // A(0) regs ready
  __builtin_amdgcn_sched_barrier(0);
  CVT_WRITE_A()                    // As <- A(0)
  AP_LOAD(1)                       // 8 loads in flight
  STAGE_B(1, 1)                    // 4 glds in flight

  // --- main loop: 8 k-tiles ---
#pragma unroll 1
  for (int kt = 0; kt < 8; ++kt) {
    const int cur = kt & 1;
    // B(kt) staged (12 newer ops: A(kt+1) 8 + B(kt+1) 4); my ds_writes drained
    asm volatile("s_waitcnt vmcnt(12) lgkmcnt(0)" ::: "memory");
    __builtin_amdgcn_sched_barrier(0);
    __builtin_amdgcn_s_barrier();
    __builtin_amdgcn_sched_barrier(0);

    short8 aF[2][4], bF[2][4];
#pragma unroll
    for (int s = 0; s < 2; ++s) {
#pragma unroll
      for (int i = 0; i < 4; ++i) {
        const int row = wr * 64 + i * 16 + lr;
        const int p   = (s * 4 + g) ^ (row & 7);
        aF[s][i] = *(const short8*)&As[row * 64 + p * 8];
      }
#pragma unroll
      for (int j = 0; j < 4; ++j) {
        const int row = wc * 64 + j * 16 + lr;
        const int p   = (s * 4 + g) ^ (row & 7);
        bF[s][j] = *(const short8*)&Bs[cur][row * 64 + p * 8];
      }
    }
    __builtin_amdgcn_s_setprio(1);
#pragma unroll
    for (int s = 0; s < 2; ++s)
#pragma unroll
      for (int i = 0; i < 4; ++i)
#pragma unroll
        for (int j = 0; j < 4; ++j)
          acc[i][j] = __builtin_amdgcn_mfma_f32_16x16x32_bf16(aF[s][i], bF[s][j], acc[i][j], 0, 0, 0);
    __builtin_amdgcn_s_setprio(0);

    asm volatile("s_waitcnt lgkmcnt(0)" ::: "memory");  // my LDS reads done
    __builtin_amdgcn_sched_barrier(0);
    __builtin_amdgcn_s_barrier();            // all reads done -> buffers reusable
    __builtin_amdgcn_sched_barrier(0);

    if (kt < 7) {
      asm volatile("s_waitcnt vmcnt(4)" ::: "memory");  // A(kt+1) regs ready (B(kt+1) newer)
      __builtin_amdgcn_sched_barrier(0);
      CVT_WRITE_A()                          // As <- A(kt+1)
      const int nk = (kt + 2 < 8) ? kt + 2 : 7;   // clamp keeps counts uniform
      AP_LOAD(nk)
      STAGE_B(nk, cur)                       // Bs[cur] free now
    }
  }
#undef AP_LOAD
#undef CVT_WRITE_A
#undef STAGE_B

  // --- epilogue: bias + bf16 + LDS repack for coalesced stores (round-2 verbatim) ---
  float bias[4];
#pragma unroll
  for (int j = 0; j < 4; ++j) {
    const int col = n0 + wc * 64 + j * 16 + lr;
    bias[j] = (col < 512) ? b1[col] : 0.0f;
  }
  unsigned short* Ls = As;               // 32 x 128 bf16 = 8 KB, reuse
  const int lrow2 = tid >> 3;            // 0..31
  const int c0    = (tid & 7) * 16;      // 16 elems = 32B per thread
  const int grB   = m0 + (lrow2 >> 4) * 64;
  __syncthreads();                       // drain pending clamped glds before reuse
#pragma unroll
  for (int i = 0; i < 4; ++i) {
#pragma unroll
    for (int j = 0; j < 4; ++j) {
      const int col  = wc * 64 + j * 16 + lr;
      const int lrow = wr * 16 + g * 4;
#pragma unroll
      for (int r = 0; r < 4; ++r)
        Ls[(lrow + r) * 128 + col] = f2bf(acc[i][j][r] + bias[j]);
    }
    __syncthreads();
    const int gr = grB + i * 16 + (lrow2 & 15);
    if (gr < M) {
      const short8 v0 = *(const short8*)&Ls[lrow2 * 128 + c0];
      const short8 v1 = *(const short8*)&Ls[lrow2 * 128 + c0 + 8];
      *(short8*)(P + (size_t)gr * 1024 + n0 + c0)     = v0;
      *(short8*)(P + (size_t)gr * 1024 + n0 + c0 + 8) = v1;
    }
    __syncthreads();
  }
}

// ---------- kernel 3: per-edge score ----------
__global__ void __launch_bounds__(256) edge_kernel(const unsigned short* __restrict__ P,
                                                   const int* __restrict__ src,
                                                   const int* __restrict__ dst,
                                                   const float* __restrict__ W2,
                                                   const float* __restrict__ b2,
                                                   float* __restrict__ out,
                                                   int E) {
  const int gw   = (blockIdx.x * 256 + threadIdx.x) >> 6;   // global wave = edge
  const int lane = threadIdx.x & 63;
  if (gw >= E) return;
  const int s = src[gw];
  const int d = dst[gw];
  const short8 va = *(const short8*)(P + (size_t)s * 1024 + lane * 8);
  const short8 vb = *(const short8*)(P + (size_t)d * 1024 + 512 + lane * 8);
  const float4 w0 = *(const float4*)(W2 + lane * 8);
  const float4 w1 = *(const float4*)(W2 + lane * 8 + 4);
  float a = 0.f, x;
  x = bf2f((unsigned short)va[0]) + bf2f((unsigned short)vb[0]); a += fmaxf(x, 0.f) * w0.x;
  x = bf2f((unsigned short)va[1]) + bf2f((unsigned short)vb[1]); a += fmaxf(x, 0.f) * w0.y;
  x = bf2f((unsigned short)va[2]) + bf2f((unsigned short)vb[2]); a += fmaxf(x, 0.f) * w0.z;
  x = bf2f((unsigned short)va[3]) + bf2f((unsigned short)vb[3]); a += fmaxf(x, 0.f) * w0.w;
  x = bf2f((unsigned short)va[4]) + bf2f((unsigned short)vb[4]); a += fmaxf(x, 0.f) * w1.x;
  x = bf2f((unsigned short)va[5]) + bf2f((unsigned short)vb[5]); a += fmaxf(x, 0.f) * w1.y;
  x = bf2f((unsigned short)va[6]) + bf2f((unsigned short)vb[6]); a += fmaxf(x, 0.f) * w1.z;
  x = bf2f((unsigned short)va[7]) + bf2f((unsigned short)vb[7]); a += fmaxf(x, 0.f) * w1.w;
#pragma unroll
  for (int o = 32; o > 0; o >>= 1) a += __shfl_down(a, o);
  if (lane == 0) out[gw] = a + b2[0];
}

// ---------- launcher ----------
extern "C" void kernel_launch(void* const* d_in, const int* in_sizes, int n_in,
                              void* d_out, int out_size, void* d_ws, size_t ws_size,
                              hipStream_t stream) {
  const float* h  = (const float*)d_in[0];
  const int*   src = (const int*)d_in[1];
  const int*   dst = (const int*)d_in[2];
  const float* W1 = (const float*)d_in[3];
  const float* b1 = (const float*)d_in[4];
  const float* W2 = (const float*)d_in[5];
  const float* b2 = (const float*)d_in[6];
  float* out = (float*)d_out;

  const int M = in_sizes[0] / 512;   // 100000 nodes
  const int E = in_sizes[1];         // 160000 edges

  char* ws = (char*)d_ws;
  unsigned short* BT = (unsigned short*)ws;                             // 1MB
  unsigned short* P  = (unsigned short*)(ws + (size_t)1024 * 512 * 2);  // M*1024 bf16

  buildBT_kernel<<<2048, 256, 0, stream>>>(W1, BT);
  const int Mtiles = (M + 127) / 128;          // 782
  gemmF_kernel<<<Mtiles * 8, 256, 0, stream>>>(h, BT, b1, P, M);
  edge_kernel<<<(E + 3) / 4, 256, 0, stream>>>(P, src, dst, W2, b2, out, E);
}

// Round 8
// 261.789 us; speedup vs baseline: 3.4366x; 1.0512x over previous
//
#include <hip/hip_runtime.h>
#include <stdint.h>

// ---------- types / helpers ----------
typedef __attribute__((ext_vector_type(8))) short short8;   // 8 x bf16 bits
typedef __attribute__((ext_vector_type(4))) float f32x4;

__device__ __forceinline__ unsigned short f2bf(float f) {
  unsigned u = __float_as_uint(f);
  u += 0x7fffu + ((u >> 16) & 1u);           // round-to-nearest-even
  return (unsigned short)(u >> 16);
}
__device__ __forceinline__ float bf2f(unsigned short u) {
  return __uint_as_float(((unsigned)u) << 16);
}

#define GLDS16(gp, lp)                                              \
  __builtin_amdgcn_global_load_lds(                                  \
      (const __attribute__((address_space(1))) void*)(gp),           \
      (__attribute__((address_space(3))) void*)(lp), 16, 0, 0)

// ---------- kernel 1: cast h (f32) -> hA (bf16) ----------
__global__ void __launch_bounds__(256) cast_h_kernel(const float* __restrict__ h,
                                                     unsigned short* __restrict__ hA,
                                                     long long total8) {
  long long i = (long long)blockIdx.x * 256 + threadIdx.x;
  if (i >= total8) return;
  const float4* p = (const float4*)(h + i * 8);
  float4 f0 = p[0], f1 = p[1];
  short8 r;
  r[0] = (short)f2bf(f0.x); r[1] = (short)f2bf(f0.y);
  r[2] = (short)f2bf(f0.z); r[3] = (short)f2bf(f0.w);
  r[4] = (short)f2bf(f1.x); r[5] = (short)f2bf(f1.y);
  r[6] = (short)f2bf(f1.z); r[7] = (short)f2bf(f1.w);
  *(short8*)(hA + i * 8) = r;
}

// ---------- kernel 2: BT[n][k] = bf16(W1[(n>=512? 512:0)+k][n&511]) ----------
__global__ void __launch_bounds__(256) buildBT_kernel(const float* __restrict__ W1,
                                                      unsigned short* __restrict__ BT) {
  int t = blockIdx.x * 256 + threadIdx.x;   // 0..524287
  int n = t >> 9;
  int k = t & 511;
  float v = W1[((size_t)((n >> 9) * 512 + k)) * 512 + (size_t)(n & 511)];
  BT[t] = f2bf(v);
}

// ---------- kernel 3: GEMM  P[M][1024](bf16) = hA[M][512] @ BT^T (+b1 cols<512) ----------
// 256x128 tile, BK=64, 256 threads (4 waves as 2Mx2N, each wave 128x64 ->
// 42.7 FLOP per LDS byte), round-2 2-barrier schedule, XOR-swizzled LDS,
// LDS-repack epilogue.
__global__ void __launch_bounds__(256, 2) gemm_kernel(const unsigned short* __restrict__ hA,
                                                      const unsigned short* __restrict__ BT,
                                                      const float* __restrict__ b1,
                                                      unsigned short* __restrict__ P,
                                                      int M) {
  __shared__ unsigned short As[256 * 64];   // 32 KB
  __shared__ unsigned short Bs[128 * 64];   // 16 KB

  // --- XCD-chunked block swizzle; logical order: n-tile fastest within an A strip ---
  const int nwg = gridDim.x;                // Mtiles*8, divisible by 8
  const int cpx = nwg >> 3;
  const int wg  = (blockIdx.x & 7) * cpx + (blockIdx.x >> 3);
  const int nt  = wg & 7;
  const int mt  = wg >> 3;
  const int m0  = mt * 256;
  const int n0  = nt * 128;

  const int tid  = threadIdx.x;
  const int lane = tid & 63;
  const int wid  = tid >> 6;
  const int wr   = wid >> 1, wc = wid & 1;   // wave = rows [wr*128, +128) x cols [wc*64, +64)
  const int lr   = lane & 15;
  const int g    = lane >> 4;                // 0..3

  f32x4 acc[8][4];
#pragma unroll
  for (int i = 0; i < 8; ++i)
#pragma unroll
    for (int j = 0; j < 4; ++j) acc[i][j] = (f32x4){0.f, 0.f, 0.f, 0.f};

  const int srow = tid >> 3;     // 0..31 (q adds +32)
  const int slot = tid & 7;      // 16B slot within 128B row

#pragma unroll 1
  for (int kt = 0; kt < 8; ++kt) {
    const int k0 = kt * 64;
    // stage A: 256 rows (8 chunks/thread)
#pragma unroll
    for (int q = 0; q < 8; ++q) {
      const int row = q * 32 + srow;
      const int gk  = k0 + ((slot ^ (row & 7)) << 3);
      const int ga  = m0 + row;
      if (ga < M) GLDS16(hA + (size_t)ga * 512 + gk, &As[row * 64 + slot * 8]);
    }
    // stage B: 128 rows (4 chunks/thread)
#pragma unroll
    for (int q = 0; q < 4; ++q) {
      const int row = q * 32 + srow;
      const int gk  = k0 + ((slot ^ (row & 7)) << 3);
      GLDS16(BT + (size_t)(n0 + row) * 512 + gk, &Bs[row * 64 + slot * 8]);
    }
    __syncthreads();   // drains vmcnt: tiles staged

#pragma unroll
    for (int s = 0; s < 2; ++s) {
      short8 aF[8], bF[4];
#pragma unroll
      for (int i = 0; i < 8; ++i) {
        const int row = wr * 128 + i * 16 + lr;
        const int p   = (s * 4 + g) ^ (row & 7);
        aF[i] = *(const short8*)&As[row * 64 + p * 8];
      }
#pragma unroll
      for (int j = 0; j < 4; ++j) {
        const int row = wc * 64 + j * 16 + lr;
        const int p   = (s * 4 + g) ^ (row & 7);
        bF[j] = *(const short8*)&Bs[row * 64 + p * 8];
      }
#pragma unroll
      for (int i = 0; i < 8; ++i)
#pragma unroll
        for (int j = 0; j < 4; ++j)
          acc[i][j] = __builtin_amdgcn_mfma_f32_16x16x32_bf16(aF[i], bF[j], acc[i][j], 0, 0, 0);
    }
    __syncthreads();   // all reads done before next stage overwrites
  }

  // --- epilogue: bias + bf16 + LDS repack for coalesced stores ---
  float bias[4];
#pragma unroll
  for (int j = 0; j < 4; ++j) {
    const int col = n0 + wc * 64 + j * 16 + lr;
    bias[j] = (col < 512) ? b1[col] : 0.0f;
  }
  unsigned short* Ls = As;               // 32 x 128 bf16 = 8 KB, reuse
  const int rowL = tid >> 3;             // 0..31
  const int c0   = (tid & 7) * 16;       // 16 elems = 32B per thread
  const int grS  = m0 + (rowL >> 4) * 128 + (rowL & 15);   // store row base (mi adds *16)
#pragma unroll
  for (int mi = 0; mi < 8; ++mi) {
    // wave (wr,wc) owns global rows m0 + wr*128 + mi*16 + (g*4+r), cols n0 + wc*64 + nf*16 + lr
#pragma unroll
    for (int nf = 0; nf < 4; ++nf) {
      const int col  = wc * 64 + nf * 16 + lr;
      const int lrow = wr * 16 + g * 4;
#pragma unroll
      for (int r = 0; r < 4; ++r)
        Ls[(lrow + r) * 128 + col] = f2bf(acc[mi][nf][r] + bias[nf]);
    }
    __syncthreads();
    const int gr = grS + mi * 16;
    if (gr < M) {
      const short8 v0 = *(const short8*)&Ls[rowL * 128 + c0];
      const short8 v1 = *(const short8*)&Ls[rowL * 128 + c0 + 8];
      *(short8*)(P + (size_t)gr * 1024 + n0 + c0)     = v0;
      *(short8*)(P + (size_t)gr * 1024 + n0 + c0 + 8) = v1;
    }
    __syncthreads();
  }
}

// ---------- kernel 4: per-edge score ----------
__global__ void __launch_bounds__(256) edge_kernel(const unsigned short* __restrict__ P,
                                                   const int* __restrict__ src,
                                                   const int* __restrict__ dst,
                                                   const float* __restrict__ W2,
                                                   const float* __restrict__ b2,
                                                   float* __restrict__ out,
                                                   int E) {
  const int gw   = (blockIdx.x * 256 + threadIdx.x) >> 6;   // global wave = edge
  const int lane = threadIdx.x & 63;
  if (gw >= E) return;
  const int s = src[gw];
  const int d = dst[gw];
  const short8 va = *(const short8*)(P + (size_t)s * 1024 + lane * 8);
  const short8 vb = *(const short8*)(P + (size_t)d * 1024 + 512 + lane * 8);
  const float4 w0 = *(const float4*)(W2 + lane * 8);
  const float4 w1 = *(const float4*)(W2 + lane * 8 + 4);
  float a = 0.f, x;
  x = bf2f((unsigned short)va[0]) + bf2f((unsigned short)vb[0]); a += fmaxf(x, 0.f) * w0.x;
  x = bf2f((unsigned short)va[1]) + bf2f((unsigned short)vb[1]); a += fmaxf(x, 0.f) * w0.y;
  x = bf2f((unsigned short)va[2]) + bf2f((unsigned short)vb[2]); a += fmaxf(x, 0.f) * w0.z;
  x = bf2f((unsigned short)va[3]) + bf2f((unsigned short)vb[3]); a += fmaxf(x, 0.f) * w0.w;
  x = bf2f((unsigned short)va[4]) + bf2f((unsigned short)vb[4]); a += fmaxf(x, 0.f) * w1.x;
  x = bf2f((unsigned short)va[5]) + bf2f((unsigned short)vb[5]); a += fmaxf(x, 0.f) * w1.y;
  x = bf2f((unsigned short)va[6]) + bf2f((unsigned short)vb[6]); a += fmaxf(x, 0.f) * w1.z;
  x = bf2f((unsigned short)va[7]) + bf2f((unsigned short)vb[7]); a += fmaxf(x, 0.f) * w1.w;
#pragma unroll
  for (int o = 32; o > 0; o >>= 1) a += __shfl_down(a, o);
  if (lane == 0) out[gw] = a + b2[0];
}

// ---------- launcher ----------
extern "C" void kernel_launch(void* const* d_in, const int* in_sizes, int n_in,
                              void* d_out, int out_size, void* d_ws, size_t ws_size,
                              hipStream_t stream) {
  const float* h  = (const float*)d_in[0];
  const int*   src = (const int*)d_in[1];
  const int*   dst = (const int*)d_in[2];
  const float* W1 = (const float*)d_in[3];
  const float* b1 = (const float*)d_in[4];
  const float* W2 = (const float*)d_in[5];
  const float* b2 = (const float*)d_in[6];
  float* out = (float*)d_out;

  const int M = in_sizes[0] / 512;   // 100000 nodes
  const int E = in_sizes[1];         // 160000 edges

  char* ws = (char*)d_ws;
  unsigned short* hA = (unsigned short*)ws;                          // M*512 bf16
  size_t off = (((size_t)M * 512 * 2) + 255) & ~(size_t)255;
  unsigned short* BT = (unsigned short*)(ws + off);                  // 1024*512 bf16
  off += (size_t)1024 * 512 * 2;
  unsigned short* P = (unsigned short*)(ws + off);                   // M*1024 bf16

  const long long total8 = (long long)M * 512 / 8;
  cast_h_kernel<<<(int)((total8 + 255) / 256), 256, 0, stream>>>(h, hA, total8);
  buildBT_kernel<<<2048, 256, 0, stream>>>(W1, BT);
  const int Mtiles = (M + 255) / 256;          // 391
  gemm_kernel<<<Mtiles * 8, 256, 0, stream>>>(hA, BT, b1, P, M);
  edge_kernel<<<(E + 3) / 4, 256, 0, stream>>>(P, src, dst, W2, b2, out, E);
}